// Round 4
// baseline (1280.559 us; speedup 1.0000x reference)
//
#include <hip/hip_runtime.h>
#include <hip/hip_bf16.h>
#include <hip/hip_fp16.h>

#define EMB 64
#define BSHIFT 11         // 2048 rows per coarse bucket
#define BROWS (1 << BSHIFT)
#define NBMAX 128         // >= ceil(200000/2048)=98
#define TILE 4096         // edges per bucket_scatter tile
#define FSH 7             // 128 rows per fine bucket
#define FROWS (1 << FSH)
#define ACCPAD 65         // LDS acc row stride (odd -> bank spread)
#define ECH 2048          // spmm edge-stage chunk
#define RCH 4096          // refine chunk

// ---- dtype-flexible loads ---------------------------------------------------
__device__ __forceinline__ float ld_elem(const void* p, long long i, int bf) {
    if (bf) return (float)((const __hip_bfloat16*)p)[i];
    return ((const float*)p)[i];
}

__device__ __forceinline__ float4 ld4_x0(const void* uw, const void* iw,
                                         int n_user_elems, long long e, int bf) {
    const void* base = uw;
    if (e >= (long long)n_user_elems) { base = iw; e -= n_user_elems; }
    if (bf) {
        uint2 r = *reinterpret_cast<const uint2*>((const unsigned short*)base + e);
        return make_float4(__uint_as_float((r.x & 0xFFFFu) << 16),
                           __uint_as_float(r.x & 0xFFFF0000u),
                           __uint_as_float((r.y & 0xFFFFu) << 16),
                           __uint_as_float(r.y & 0xFFFF0000u));
    }
    return *reinterpret_cast<const float4*>((const float*)base + e);
}

__device__ __forceinline__ float4 ld4_f16(const __half* g, long long e) {
    uint2 r = *reinterpret_cast<const uint2*>(g + e);
    union { unsigned int u; __half2 h; } c0, c1;
    c0.u = r.x; c1.u = r.y;
    float2 f0 = __half22float2(c0.h), f1 = __half22float2(c1.h);
    return make_float4(f0.x, f0.y, f1.x, f1.y);
}

// ---- coarse histogram (LDS-privatized) + fused dtype probe ------------------
__global__ void hist_coarse(const int* __restrict__ rows, int* __restrict__ counts, int nnz,
                            const unsigned short* __restrict__ v16, int* __restrict__ flag) {
    __shared__ int h[NBMAX];
    int t = threadIdx.x;
    if (t < NBMAX) h[t] = 0;
    __syncthreads();
    int tid = blockIdx.x * blockDim.x + t;
    int stride = gridDim.x * blockDim.x;
    for (int e = tid; e < nnz; e += stride) atomicAdd(&h[rows[e] >> BSHIFT], 1);
    __syncthreads();
    if (t < NBMAX) { int v = h[t]; if (v) atomicAdd(&counts[t], v); }
    if (tid == 0) {
        int hits = 0;
        for (int i = 0; i < 256; ++i) {
            unsigned int hb = v16[i] >> 8;
            unsigned int ex = hb & 0x7F;
            if (hb < 0x80 && ex >= 0x30 && ex < 0x40) hits++;
        }
        *flag = (hits >= 200) ? 1 : 0;   // 1 = bf16, 0 = fp32
    }
}

// ---- tiny scan over coarse buckets (1 block) --------------------------------
__global__ void scan_coarse(const int* __restrict__ counts, int* __restrict__ cptr,
                            int* __restrict__ bcur, int nb) {
    __shared__ int lds[128];
    int t = threadIdx.x;                 // blockDim = 128 >= nb
    int v = (t < nb) ? counts[t] : 0;
    lds[t] = v;
    __syncthreads();
    for (int off = 1; off < 128; off <<= 1) {
        int x = lds[t];
        int a = (t >= off) ? lds[t - off] : 0;
        __syncthreads();
        lds[t] = x + a;
        __syncthreads();
    }
    if (t < nb) { int excl = lds[t] - v; cptr[t] = excl; bcur[t] = excl; }
    if (t == 0) cptr[nb] = lds[127];
}

// ---- pass A: LDS-binned coarse bucket scatter (coalesced staged writes) -----
// staged record: (val fp32, meta = (lrow11<<18)|col)
__global__ void bucket_scatter(const void* __restrict__ vals, const int* __restrict__ rows,
                               const int* __restrict__ cols, int* __restrict__ bcur,
                               float2* __restrict__ staged, int nnz, int nbuck,
                               const int* __restrict__ flagp) {
    __shared__ int hist[NBMAX];
    __shared__ int exb[NBMAX];
    __shared__ int gb[NBMAX];
    __shared__ int sc[NBMAX];
    __shared__ float2 st[TILE];
    __shared__ int bkt[TILE];
    int t = threadIdx.x;
    int bf = *flagp;

    for (int tile = blockIdx.x * TILE; tile < nnz; tile += gridDim.x * TILE) {
        int cnt = min(TILE, nnz - tile);
        for (int i = t; i < NBMAX; i += 256) hist[i] = 0;
        __syncthreads();

        int   myb[16], myo[16], mmeta[16];
        float mv[16];
#pragma unroll
        for (int k = 0; k < 16; ++k) {
            int i = tile + k * 256 + t;            // coalesced
            if (i < nnz && (k * 256 + t) < cnt) {
                int r = rows[i], c = cols[i];
                mv[k]    = ld_elem(vals, i, bf);
                myb[k]   = r >> BSHIFT;
                mmeta[k] = ((r & (BROWS - 1)) << 18) | c;
                myo[k]   = atomicAdd(&hist[myb[k]], 1);
            } else myb[k] = -1;
        }
        __syncthreads();

        if (t < NBMAX) sc[t] = hist[t];
        __syncthreads();
        for (int off = 1; off < NBMAX; off <<= 1) {
            int v = 0;
            if (t < NBMAX) { v = sc[t]; if (t >= off) v += sc[t - off]; }
            __syncthreads();
            if (t < NBMAX) sc[t] = v;
            __syncthreads();
        }
        if (t < NBMAX) {
            exb[t] = sc[t] - hist[t];
            if (t < nbuck && hist[t] > 0) gb[t] = atomicAdd(&bcur[t], hist[t]);
        }
        __syncthreads();

#pragma unroll
        for (int k = 0; k < 16; ++k) {
            if (myb[k] >= 0) {
                int p = exb[myb[k]] + myo[k];
                st[p]  = make_float2(mv[k], __int_as_float(mmeta[k]));
                bkt[p] = myb[k];
            }
        }
        __syncthreads();

        for (int p = t; p < cnt; p += 256) {
            int b = bkt[p];
            staged[gb[b] + (p - exb[b])] = st[p];
        }
        __syncthreads();
    }
}

// ---- pass B: refine each coarse bucket into 16 fine (128-row) buckets -------
// One block per coarse bucket; all reorder work in LDS; coalesced IO.
__global__ void bucket_refine(const int* __restrict__ cptr,
                              const float2* __restrict__ staged,
                              float2* __restrict__ edges,
                              int* __restrict__ fptr, int nbuck) {
    __shared__ float2 st[RCH];
    __shared__ unsigned short fo[RCH];
    __shared__ unsigned short idx[RCH];
    __shared__ int cnt16[16], exb16[16], ccnt[16], cexb[16], gbl[16], cur[16];
    int b = blockIdx.x;
    int t = threadIdx.x;
    int cbeg = cptr[b], cend = cptr[b + 1];

    // pass 1: total fine counts for this coarse bucket
    if (t < 16) cnt16[t] = 0;
    __syncthreads();
    const int* sm = (const int*)staged;
    for (int i = cbeg + t; i < cend; i += 256) {
        int f = (sm[2 * i + 1] >> 25) & 15;
        atomicAdd(&cnt16[f], 1);
    }
    __syncthreads();
    if (t == 0) {
        int run = 0;
        for (int f = 0; f < 16; ++f) { exb16[f] = run; run += cnt16[f]; }
    }
    __syncthreads();
    if (t < 16) { fptr[b * 16 + t] = cbeg + exb16[t]; cur[t] = 0; }
    if (b == nbuck - 1 && t == 0) fptr[nbuck * 16] = cend;
    __syncthreads();

    // pass 2: chunked regroup
    int len = cend - cbeg;
    for (int off = 0; off < len; off += RCH) {
        int c = min(RCH, len - off);
        if (t < 16) ccnt[t] = 0;
        __syncthreads();
        for (int i = t; i < c; i += 256) {
            float2 rec = staged[cbeg + off + i];
            st[i] = rec;
            int f = (__float_as_int(rec.y) >> 25) & 15;
            int o = atomicAdd(&ccnt[f], 1);
            fo[i] = (unsigned short)((f << 12) | o);   // o < 4096
        }
        __syncthreads();
        if (t == 0) {
            int run = 0;
            for (int f = 0; f < 16; ++f) {
                cexb[f] = run; run += ccnt[f];
                gbl[f] = cbeg + exb16[f] + cur[f];
                cur[f] += ccnt[f];
            }
        }
        __syncthreads();
        for (int i = t; i < c; i += 256) {
            int v = fo[i];
            idx[cexb[v >> 12] + (v & 4095)] = (unsigned short)i;
        }
        __syncthreads();
        for (int p = t; p < c; p += 256) {
            float2 rec = st[idx[p]];
            int f = (__float_as_int(rec.y) >> 25) & 15;
            edges[gbl[f] + (p - cexb[f])] = rec;
        }
        __syncthreads();
    }
}

// ---- SpMM: one block per 128-row fine bucket, LDS fp32 accumulation ---------
// GMODE: 0 = gather x0 (inputs, dtype via flag), 1 = gather fp16 g
// OMODE: 1 = write g' = x0 + acc as fp16, 3 = final (x0+acc)*0.25 (dtype via flag)
template <int GMODE, int OMODE>
__global__ void __launch_bounds__(512) spmm_lds(const int* __restrict__ fptr,
                          const float2* __restrict__ edges,
                          const void* __restrict__ uw, const void* __restrict__ iw,
                          int n_user_elems,
                          const __half* __restrict__ gin, void* __restrict__ gout,
                          int nrows, const int* __restrict__ flagp) {
    __shared__ float acc[FROWS * ACCPAD];   // 33.3 KB
    __shared__ float2 est[ECH];             // 16 KB
    int t = threadIdx.x;
    int bid = blockIdx.x;
    int rlo = bid << FSH;
    int nr = min(FROWS, nrows - rlo);
    int bf = *flagp;
    for (int i = t; i < FROWS * ACCPAD; i += 512) acc[i] = 0.f;
    int beg = fptr[bid], end = fptr[bid + 1];
    int gid = t >> 4, l = t & 15;           // 32 groups x 16 lanes
    __syncthreads();

#define GATH(M, X) { \
        long long ce = (long long)((M) & 0x3FFFF) * EMB + l * 4; \
        if (GMODE == 0) X = ld4_x0(uw, iw, n_user_elems, ce, bf); \
        else            X = ld4_f16(gin, ce); }
#define LACC(R, M, X) { \
        float* ap = &acc[((M) >> 18 & (FROWS - 1)) * ACCPAD + l * 4]; \
        atomicAdd(ap + 0, (R).x * (X).x); atomicAdd(ap + 1, (R).x * (X).y); \
        atomicAdd(ap + 2, (R).x * (X).z); atomicAdd(ap + 3, (R).x * (X).w); }

    for (int off = beg; off < end; off += ECH) {
        int c = min(ECH, end - off);
        for (int i = t; i < c; i += 512) est[i] = edges[off + i];
        __syncthreads();
        int i = gid;
        for (; i + 32 < c; i += 64) {        // 2-wide ILP per group
            float2 r0 = est[i], r1 = est[i + 32];
            int m0 = __float_as_int(r0.y), m1 = __float_as_int(r1.y);
            float4 x0, x1;
            GATH(m0, x0); GATH(m1, x1);
            LACC(r0, m0, x0); LACC(r1, m1, x1);
        }
        if (i < c) {
            float2 r0 = est[i];
            int m0 = __float_as_int(r0.y);
            float4 x0; GATH(m0, x0);
            LACC(r0, m0, x0);
        }
        __syncthreads();
    }
#undef GATH
#undef LACC

    // epilogue: out = x0 + acc (scaled for final layer)
    for (int i4 = t * 4; i4 < nr * EMB; i4 += 512 * 4) {
        int r = i4 >> 6, d = i4 & 63;
        long long ge = (long long)(rlo + r) * EMB + d;
        float4 x0v = ld4_x0(uw, iw, n_user_elems, ge, bf);
        const float* ap = &acc[r * ACCPAD + d];
        float o0 = x0v.x + ap[0], o1 = x0v.y + ap[1];
        float o2 = x0v.z + ap[2], o3 = x0v.w + ap[3];
        if (OMODE == 1) {
            union { __half2 h; unsigned int u; } p0, p1;
            p0.h = __floats2half2_rn(o0, o1);
            p1.h = __floats2half2_rn(o2, o3);
            uint2 out; out.x = p0.u; out.y = p1.u;
            reinterpret_cast<uint2*>(gout)[ge >> 2] = out;
        } else {
            o0 *= 0.25f; o1 *= 0.25f; o2 *= 0.25f; o3 *= 0.25f;
            if (bf) {
                __hip_bfloat16 b0 = (__hip_bfloat16)o0, b1 = (__hip_bfloat16)o1;
                __hip_bfloat16 b2 = (__hip_bfloat16)o2, b3 = (__hip_bfloat16)o3;
                unsigned short s0 = *reinterpret_cast<unsigned short*>(&b0);
                unsigned short s1 = *reinterpret_cast<unsigned short*>(&b1);
                unsigned short s2 = *reinterpret_cast<unsigned short*>(&b2);
                unsigned short s3 = *reinterpret_cast<unsigned short*>(&b3);
                uint2 out;
                out.x = (unsigned int)s0 | ((unsigned int)s1 << 16);
                out.y = (unsigned int)s2 | ((unsigned int)s3 << 16);
                reinterpret_cast<uint2*>(gout)[ge >> 2] = out;
            } else {
                reinterpret_cast<float4*>(gout)[ge >> 2] = make_float4(o0, o1, o2, o3);
            }
        }
    }
}

extern "C" void kernel_launch(void* const* d_in, const int* in_sizes, int n_in,
                              void* d_out, int out_size, void* d_ws, size_t ws_size,
                              hipStream_t stream) {
    const void* uw   = d_in[0];
    const void* iw   = d_in[1];
    const void* vals = d_in[2];
    const int*  rows = (const int*)d_in[3];
    const int*  cols = (const int*)d_in[4];

    const int n_user = in_sizes[0];                // 6.4M elems
    const int total  = in_sizes[0] + in_sizes[1];  // 12.8M elems
    const int nnz    = in_sizes[2];                // 1M edges
    const int nrows  = total / EMB;                // 200K
    const int nbuck  = (nrows + BROWS - 1) >> BSHIFT;   // 98 coarse
    const int nfine  = (nrows + FROWS - 1) >> FSH;      // 1563 fine

    // ---- workspace layout (256B-aligned) ----
    char* p = (char*)d_ws;
    auto alloc = [&](size_t bytes) { char* q = p; p += (bytes + 255) & ~(size_t)255; return q; };
    int*    flag    = (int*)   alloc(sizeof(int));
    int*    counts  = (int*)   alloc(NBMAX * sizeof(int));
    int*    cptr    = (int*)   alloc((NBMAX + 1) * sizeof(int));
    int*    bcur    = (int*)   alloc(NBMAX * sizeof(int));
    int*    fptr    = (int*)   alloc((NBMAX * 16 + 1) * sizeof(int));
    float2* staged  = (float2*)alloc((size_t)nnz * sizeof(float2));
    float2* edges   = (float2*)alloc((size_t)nnz * sizeof(float2));
    size_t used = (size_t)(p - (char*)d_ws);
    size_t avail = (ws_size > used) ? ws_size - used : 0;

    const size_t g_f16 = (size_t)total * sizeof(__half);  // 25.6 MB
    __half *g2, *g3;
    if (avail >= 2 * g_f16 + 512) { g2 = (__half*)alloc(g_f16); g3 = (__half*)alloc(g_f16); }
    else { g2 = (__half*)d_out; g3 = (__half*)alloc(g_f16); }  // d_out dead-staged, overwritten at end

    // ---- bucket-grouped edge build (no row-exact CSR needed) ----
    hipMemsetAsync(counts, 0, NBMAX * sizeof(int), stream);
    hist_coarse<<<120, 256, 0, stream>>>(rows, counts, nnz, (const unsigned short*)vals, flag);
    scan_coarse<<<1, 128, 0, stream>>>(counts, cptr, bcur, nbuck);
    const int ntiles = (nnz + TILE - 1) / TILE;   // 245
    bucket_scatter<<<ntiles, 256, 0, stream>>>(vals, rows, cols, bcur, staged, nnz, nbuck, flag);
    bucket_refine<<<nbuck, 256, 0, stream>>>(cptr, staged, edges, fptr, nbuck);

    // ---- 3 SpMM layers (Horner), fp16 inter-layer staging ----
    spmm_lds<0, 1><<<nfine, 512, 0, stream>>>(fptr, edges, uw, iw, n_user,
                                              nullptr, g2, nrows, flag);
    spmm_lds<1, 1><<<nfine, 512, 0, stream>>>(fptr, edges, uw, iw, n_user,
                                              g2, g3, nrows, flag);
    spmm_lds<1, 3><<<nfine, 512, 0, stream>>>(fptr, edges, uw, iw, n_user,
                                              g3, d_out, nrows, flag);
}

// Round 5
// 272.115 us; speedup vs baseline: 4.7059x; 4.7059x over previous
//
#include <hip/hip_runtime.h>
#include <hip/hip_bf16.h>
#include <hip/hip_fp16.h>

#define EMB 64
#define BSHIFT 11         // 2048 rows per coarse bucket
#define BROWS (1 << BSHIFT)
#define NBMAX 128         // >= ceil(200000/2048)=98
#define TILE 4096         // edges per bucket_scatter tile

// ---- dtype-flexible loads ---------------------------------------------------
__device__ __forceinline__ float ld_elem(const void* p, long long i, int bf) {
    if (bf) return (float)((const __hip_bfloat16*)p)[i];
    return ((const float*)p)[i];
}

__device__ __forceinline__ float4 ld4_x0(const void* uw, const void* iw,
                                         int n_user_elems, long long e, int bf) {
    const void* base = uw;
    if (e >= (long long)n_user_elems) { base = iw; e -= n_user_elems; }
    if (bf) {
        uint2 r = *reinterpret_cast<const uint2*>((const unsigned short*)base + e);
        return make_float4(__uint_as_float((r.x & 0xFFFFu) << 16),
                           __uint_as_float(r.x & 0xFFFF0000u),
                           __uint_as_float((r.y & 0xFFFFu) << 16),
                           __uint_as_float(r.y & 0xFFFF0000u));
    }
    return *reinterpret_cast<const float4*>((const float*)base + e);
}

__device__ __forceinline__ float4 ld4_f16(const __half* g, long long e) {
    uint2 r = *reinterpret_cast<const uint2*>(g + e);
    union { unsigned int u; __half2 h; } c0, c1;
    c0.u = r.x; c1.u = r.y;
    float2 f0 = __half22float2(c0.h), f1 = __half22float2(c1.h);
    return make_float4(f0.x, f0.y, f1.x, f1.y);
}

// ---- coarse histogram (LDS-privatized) + fused dtype probe ------------------
__global__ void hist_coarse(const int* __restrict__ rows, int* __restrict__ counts, int nnz,
                            const unsigned short* __restrict__ v16, int* __restrict__ flag) {
    __shared__ int h[NBMAX];
    int t = threadIdx.x;
    if (t < NBMAX) h[t] = 0;
    __syncthreads();
    int tid = blockIdx.x * blockDim.x + t;
    int stride = gridDim.x * blockDim.x;
    for (int e = tid; e < nnz; e += stride) atomicAdd(&h[rows[e] >> BSHIFT], 1);
    __syncthreads();
    if (t < NBMAX) { int v = h[t]; if (v) atomicAdd(&counts[t], v); }
    if (tid == 0) {
        int hits = 0;
        for (int i = 0; i < 256; ++i) {
            unsigned int hb = v16[i] >> 8;
            unsigned int ex = hb & 0x7F;
            if (hb < 0x80 && ex >= 0x30 && ex < 0x40) hits++;
        }
        *flag = (hits >= 200) ? 1 : 0;   // 1 = bf16, 0 = fp32
    }
}

// ---- tiny scan over coarse buckets (1 block) --------------------------------
__global__ void scan_coarse(const int* __restrict__ counts, int* __restrict__ cptr,
                            int* __restrict__ bcur, int nb) {
    __shared__ int lds[128];
    int t = threadIdx.x;                 // blockDim = 128 >= nb
    int v = (t < nb) ? counts[t] : 0;
    lds[t] = v;
    __syncthreads();
    for (int off = 1; off < 128; off <<= 1) {
        int x = lds[t];
        int a = (t >= off) ? lds[t - off] : 0;
        __syncthreads();
        lds[t] = x + a;
        __syncthreads();
    }
    if (t < nb) { int excl = lds[t] - v; cptr[t] = excl; bcur[t] = excl; }
    if (t == 0) cptr[nb] = lds[127];
}

// ---- pass A: LDS-binned coarse bucket scatter (coalesced staged writes) -----
// staged record: (val fp32, meta = (lrow11<<18)|col)
__global__ void bucket_scatter(const void* __restrict__ vals, const int* __restrict__ rows,
                               const int* __restrict__ cols, int* __restrict__ bcur,
                               float2* __restrict__ staged, int nnz, int nbuck,
                               const int* __restrict__ flagp) {
    __shared__ int hist[NBMAX];
    __shared__ int exb[NBMAX];
    __shared__ int gb[NBMAX];
    __shared__ int sc[NBMAX];
    __shared__ float2 st[TILE];
    __shared__ int bkt[TILE];
    int t = threadIdx.x;
    int bf = *flagp;

    for (int tile = blockIdx.x * TILE; tile < nnz; tile += gridDim.x * TILE) {
        int cnt = min(TILE, nnz - tile);
        for (int i = t; i < NBMAX; i += 256) hist[i] = 0;
        __syncthreads();

        int   myb[16], myo[16], mmeta[16];
        float mv[16];
#pragma unroll
        for (int k = 0; k < 16; ++k) {
            int i = tile + k * 256 + t;            // coalesced
            if (i < nnz && (k * 256 + t) < cnt) {
                int r = rows[i], c = cols[i];
                mv[k]    = ld_elem(vals, i, bf);
                myb[k]   = r >> BSHIFT;
                mmeta[k] = ((r & (BROWS - 1)) << 18) | c;
                myo[k]   = atomicAdd(&hist[myb[k]], 1);
            } else myb[k] = -1;
        }
        __syncthreads();

        if (t < NBMAX) sc[t] = hist[t];
        __syncthreads();
        for (int off = 1; off < NBMAX; off <<= 1) {
            int v = 0;
            if (t < NBMAX) { v = sc[t]; if (t >= off) v += sc[t - off]; }
            __syncthreads();
            if (t < NBMAX) sc[t] = v;
            __syncthreads();
        }
        if (t < NBMAX) {
            exb[t] = sc[t] - hist[t];
            if (t < nbuck && hist[t] > 0) gb[t] = atomicAdd(&bcur[t], hist[t]);
        }
        __syncthreads();

#pragma unroll
        for (int k = 0; k < 16; ++k) {
            if (myb[k] >= 0) {
                int p = exb[myb[k]] + myo[k];
                st[p]  = make_float2(mv[k], __int_as_float(mmeta[k]));
                bkt[p] = myb[k];
            }
        }
        __syncthreads();

        for (int p = t; p < cnt; p += 256) {
            int b = bkt[p];
            staged[gb[b] + (p - exb[b])] = st[p];
        }
        __syncthreads();
    }
}

// ---- pass B (fused): per-bucket row hist + LDS scan + row_ptr + placement ---
// One block per coarse bucket. Produces global row-exact CSR.
__global__ void bucket_csr(const int* __restrict__ cptr,
                           const float2* __restrict__ staged,
                           float2* __restrict__ edges,
                           int* __restrict__ row_ptr, int nrows, int nbuck) {
    __shared__ int rcnt[BROWS];   // 8 KB: per-row counts -> excl offsets -> cursors
    __shared__ int ssum[256];
    int b = blockIdx.x;
    int t = threadIdx.x;          // 256 threads
    int cbeg = cptr[b], cend = cptr[b + 1];
    int rlo = b << BSHIFT;
    int nr = min(BROWS, nrows - rlo);

    for (int i = t; i < BROWS; i += 256) rcnt[i] = 0;
    __syncthreads();

    // pass 1: per-row counts (LDS atomics, low contention)
    const int* sm = (const int*)staged;
    for (int i = cbeg + t; i < cend; i += 256) {
        int lr = (sm[2 * i + 1] >> 18) & (BROWS - 1);
        atomicAdd(&rcnt[lr], 1);
    }
    __syncthreads();

    // exclusive scan of 2048 counters: 8 per thread + block scan
    int base = t * 8;
    int loc[8]; int s = 0;
#pragma unroll
    for (int k = 0; k < 8; ++k) { loc[k] = rcnt[base + k]; s += loc[k]; }
    ssum[t] = s;
    __syncthreads();
    for (int off = 1; off < 256; off <<= 1) {
        int x = ssum[t];
        int a = (t >= off) ? ssum[t - off] : 0;
        __syncthreads();
        ssum[t] = x + a;
        __syncthreads();
    }
    int run = (t > 0) ? ssum[t - 1] : 0;
#pragma unroll
    for (int k = 0; k < 8; ++k) { int c = loc[k]; rcnt[base + k] = run; run += c; }
    __syncthreads();

    // emit global row_ptr (coalesced)
    for (int i = t; i < nr; i += 256) row_ptr[rlo + i] = cbeg + rcnt[i];
    if (b == nbuck - 1 && t == 0) row_ptr[nrows] = cend;

    // pass 2: row-exact placement (L2-local window, LDS cursors)
    for (int i = cbeg + t; i < cend; i += 256) {
        float2 rec = staged[i];
        int meta = __float_as_int(rec.y);
        int lr = (meta >> 18) & (BROWS - 1);
        int c  = meta & 0x3FFFF;
        int pos = atomicAdd(&rcnt[lr], 1);
        edges[cbeg + pos] = make_float2(rec.x, __int_as_float(c));
    }
}

// ---- gather-only SpMM: 4 rows per wave, 16 lanes per row, lane = 4 dims ----
// GMODE: 0 = gather x0 (inputs, dtype via flag), 1 = gather fp16 g
// OMODE: 1 = write g' = x0 + acc as fp16, 3 = final (x0+acc)*0.25 (dtype via flag)
template <int GMODE, int OMODE>
__global__ void spmm_csr4(const int* __restrict__ row_ptr,
                          const float2* __restrict__ edges,
                          const void* __restrict__ uw, const void* __restrict__ iw,
                          int n_user_elems,
                          const __half* __restrict__ gin, void* __restrict__ gout,
                          int nrows, const int* __restrict__ flagp) {
    int tid  = blockIdx.x * blockDim.x + threadIdx.x;
    int wave = tid >> 6;
    int lane = threadIdx.x & 63;
    int g    = lane >> 4;          // row slot within wave (0..3)
    int l    = lane & 15;          // dim quad: covers dims [4l, 4l+3]
    int wid  = wave * 4 + g;
    if (wid >= nrows) return;
    int bf = *flagp;
    int beg = row_ptr[wid], end = row_ptr[wid + 1];
    float a0 = 0.f, a1 = 0.f, a2 = 0.f, a3 = 0.f;

#define GATHER(E, X) { \
        long long ce = (long long)__float_as_int((E).y) * EMB + l * 4; \
        if (GMODE == 0) X = ld4_x0(uw, iw, n_user_elems, ce, bf); \
        else            X = ld4_f16(gin, ce); }
#define ACC(E, X) { a0 += (E).x * (X).x; a1 += (E).x * (X).y; \
                    a2 += (E).x * (X).z; a3 += (E).x * (X).w; }

    int j = beg;
    for (; j + 4 <= end; j += 4) {
        float2 e0 = edges[j], e1 = edges[j + 1], e2 = edges[j + 2], e3 = edges[j + 3];
        float4 xa, xb, xc, xd;
        GATHER(e0, xa); GATHER(e1, xb); GATHER(e2, xc); GATHER(e3, xd);
        ACC(e0, xa); ACC(e1, xb); ACC(e2, xc); ACC(e3, xd);
    }
    if (j + 2 <= end) {
        float2 e0 = edges[j], e1 = edges[j + 1];
        float4 xa, xb;
        GATHER(e0, xa); GATHER(e1, xb);
        ACC(e0, xa); ACC(e1, xb);
        j += 2;
    }
    if (j < end) {
        float2 e0 = edges[j];
        float4 xa; GATHER(e0, xa);
        ACC(e0, xa);
    }
#undef GATHER
#undef ACC

    long long re = (long long)wid * EMB + l * 4;
    float4 x0v = ld4_x0(uw, iw, n_user_elems, re, bf);
    float o0 = x0v.x + a0, o1 = x0v.y + a1, o2 = x0v.z + a2, o3 = x0v.w + a3;

    if (OMODE == 1) {
        __half2 h01 = __floats2half2_rn(o0, o1);
        __half2 h23 = __floats2half2_rn(o2, o3);
        union { __half2 h; unsigned int u; } p0, p1;
        p0.h = h01; p1.h = h23;
        uint2 out; out.x = p0.u; out.y = p1.u;
        reinterpret_cast<uint2*>(gout)[re >> 2] = out;
    } else {
        o0 *= 0.25f; o1 *= 0.25f; o2 *= 0.25f; o3 *= 0.25f;
        if (bf) {
            __hip_bfloat16 b0 = (__hip_bfloat16)o0, b1 = (__hip_bfloat16)o1;
            __hip_bfloat16 b2 = (__hip_bfloat16)o2, b3 = (__hip_bfloat16)o3;
            unsigned short s0 = *reinterpret_cast<unsigned short*>(&b0);
            unsigned short s1 = *reinterpret_cast<unsigned short*>(&b1);
            unsigned short s2 = *reinterpret_cast<unsigned short*>(&b2);
            unsigned short s3 = *reinterpret_cast<unsigned short*>(&b3);
            uint2 out;
            out.x = (unsigned int)s0 | ((unsigned int)s1 << 16);
            out.y = (unsigned int)s2 | ((unsigned int)s3 << 16);
            reinterpret_cast<uint2*>(gout)[re >> 2] = out;
        } else {
            reinterpret_cast<float4*>(gout)[re >> 2] = make_float4(o0, o1, o2, o3);
        }
    }
}

extern "C" void kernel_launch(void* const* d_in, const int* in_sizes, int n_in,
                              void* d_out, int out_size, void* d_ws, size_t ws_size,
                              hipStream_t stream) {
    const void* uw   = d_in[0];
    const void* iw   = d_in[1];
    const void* vals = d_in[2];
    const int*  rows = (const int*)d_in[3];
    const int*  cols = (const int*)d_in[4];

    const int n_user = in_sizes[0];                // 6.4M elems
    const int total  = in_sizes[0] + in_sizes[1];  // 12.8M elems
    const int nnz    = in_sizes[2];                // 1M edges
    const int nrows  = total / EMB;                // 200K
    const int nbuck  = (nrows + BROWS - 1) >> BSHIFT;   // 98 coarse

    // ---- workspace layout (256B-aligned) ----
    char* p = (char*)d_ws;
    auto alloc = [&](size_t bytes) { char* q = p; p += (bytes + 255) & ~(size_t)255; return q; };
    int*    flag    = (int*)   alloc(sizeof(int));
    int*    counts  = (int*)   alloc(NBMAX * sizeof(int));
    int*    cptr    = (int*)   alloc((NBMAX + 1) * sizeof(int));
    int*    bcur    = (int*)   alloc(NBMAX * sizeof(int));
    int*    row_ptr = (int*)   alloc((size_t)(nrows + 1) * sizeof(int));
    float2* staged  = (float2*)alloc((size_t)nnz * sizeof(float2));
    float2* edges   = (float2*)alloc((size_t)nnz * sizeof(float2));
    size_t used = (size_t)(p - (char*)d_ws);
    size_t avail = (ws_size > used) ? ws_size - used : 0;

    const size_t g_f16 = (size_t)total * sizeof(__half);  // 25.6 MB
    __half *g2, *g3;
    if (avail >= 2 * g_f16 + 512) { g2 = (__half*)alloc(g_f16); g3 = (__half*)alloc(g_f16); }
    else { g2 = (__half*)d_out; g3 = (__half*)alloc(g_f16); }  // d_out dead-staged, overwritten at end

    // ---- row-exact CSR via coarse buckets (cheap build) ----
    hipMemsetAsync(counts, 0, NBMAX * sizeof(int), stream);
    hist_coarse<<<120, 256, 0, stream>>>(rows, counts, nnz, (const unsigned short*)vals, flag);
    scan_coarse<<<1, 128, 0, stream>>>(counts, cptr, bcur, nbuck);
    const int ntiles = (nnz + TILE - 1) / TILE;   // 245
    bucket_scatter<<<ntiles, 256, 0, stream>>>(vals, rows, cols, bcur, staged, nnz, nbuck, flag);
    bucket_csr<<<nbuck, 256, 0, stream>>>(cptr, staged, edges, row_ptr, nrows, nbuck);

    // ---- 3 gather-only SpMM layers (Horner), fp16 inter-layer staging ----
    const int nwaves = (nrows + 3) / 4;
    const int rb = (nwaves * 64 + 255) / 256;
    spmm_csr4<0, 1><<<rb, 256, 0, stream>>>(row_ptr, edges, uw, iw, n_user,
                                            nullptr, g2, nrows, flag);
    spmm_csr4<1, 1><<<rb, 256, 0, stream>>>(row_ptr, edges, uw, iw, n_user,
                                            g2, g3, nrows, flag);
    spmm_csr4<1, 3><<<rb, 256, 0, stream>>>(row_ptr, edges, uw, iw, n_user,
                                            g3, d_out, nrows, flag);
}

// Round 6
// 254.699 us; speedup vs baseline: 5.0277x; 1.0684x over previous
//
#include <hip/hip_runtime.h>
#include <hip/hip_bf16.h>
#include <hip/hip_fp16.h>

#define EMB 64
#define BSHIFT 11         // 2048 rows per coarse bucket
#define BROWS (1 << BSHIFT)
#define NBMAX 128         // >= ceil(200000/2048)=98
#define TILE 4096         // edges per bucket_scatter tile

// ---- dtype-flexible loads ---------------------------------------------------
__device__ __forceinline__ float ld_elem(const void* p, long long i, int bf) {
    if (bf) return (float)((const __hip_bfloat16*)p)[i];
    return ((const float*)p)[i];
}

struct f8 { float4 a, b; };

// load 8 consecutive elems (16B fp16/bf16, 32B fp32) — e is a multiple of 8
__device__ __forceinline__ f8 ld8_x0(const void* uw, const void* iw,
                                     int n_user_elems, long long e, int bf) {
    const void* base = uw;
    if (e >= (long long)n_user_elems) { base = iw; e -= n_user_elems; }
    f8 r;
    if (bf) {
        uint4 q = *reinterpret_cast<const uint4*>((const unsigned short*)base + e);
        r.a = make_float4(__uint_as_float((q.x & 0xFFFFu) << 16),
                          __uint_as_float(q.x & 0xFFFF0000u),
                          __uint_as_float((q.y & 0xFFFFu) << 16),
                          __uint_as_float(q.y & 0xFFFF0000u));
        r.b = make_float4(__uint_as_float((q.z & 0xFFFFu) << 16),
                          __uint_as_float(q.z & 0xFFFF0000u),
                          __uint_as_float((q.w & 0xFFFFu) << 16),
                          __uint_as_float(q.w & 0xFFFF0000u));
    } else {
        const float4* f = reinterpret_cast<const float4*>((const float*)base + e);
        r.a = f[0]; r.b = f[1];
    }
    return r;
}

__device__ __forceinline__ f8 ld8_f16(const __half* g, long long e) {
    uint4 q = *reinterpret_cast<const uint4*>(g + e);
    union { unsigned int u; __half2 h; } c;
    f8 r;
    c.u = q.x; float2 f0 = __half22float2(c.h);
    c.u = q.y; float2 f1 = __half22float2(c.h);
    c.u = q.z; float2 f2 = __half22float2(c.h);
    c.u = q.w; float2 f3 = __half22float2(c.h);
    r.a = make_float4(f0.x, f0.y, f1.x, f1.y);
    r.b = make_float4(f2.x, f2.y, f3.x, f3.y);
    return r;
}

// ---- coarse histogram (LDS-privatized) + parallel dtype probe ---------------
__global__ void hist_coarse(const int* __restrict__ rows, int* __restrict__ counts, int nnz,
                            const unsigned short* __restrict__ v16, int* __restrict__ flag) {
    __shared__ int h[NBMAX];
    __shared__ int probe;
    int t = threadIdx.x;
    if (t < NBMAX) h[t] = 0;
    if (t == 0) probe = 0;
    __syncthreads();
    int tid = blockIdx.x * blockDim.x + t;
    int stride = gridDim.x * blockDim.x;
    for (int e = tid; e < nnz; e += stride) atomicAdd(&h[rows[e] >> BSHIFT], 1);
    if (blockIdx.x == 0) {           // parallel probe: 256 threads x 1 value
        unsigned int hb = v16[t] >> 8;
        unsigned int ex = hb & 0x7F;
        if (hb < 0x80 && ex >= 0x30 && ex < 0x40) atomicAdd(&probe, 1);
    }
    __syncthreads();
    if (t < NBMAX) { int v = h[t]; if (v) atomicAdd(&counts[t], v); }
    if (blockIdx.x == 0 && t == 0) *flag = (probe >= 200) ? 1 : 0;
}

// ---- tiny scan over coarse buckets (1 block) --------------------------------
__global__ void scan_coarse(const int* __restrict__ counts, int* __restrict__ cptr,
                            int* __restrict__ bcur, int nb) {
    __shared__ int lds[128];
    int t = threadIdx.x;                 // blockDim = 128 >= nb
    int v = (t < nb) ? counts[t] : 0;
    lds[t] = v;
    __syncthreads();
    for (int off = 1; off < 128; off <<= 1) {
        int x = lds[t];
        int a = (t >= off) ? lds[t - off] : 0;
        __syncthreads();
        lds[t] = x + a;
        __syncthreads();
    }
    if (t < nb) { int excl = lds[t] - v; cptr[t] = excl; bcur[t] = excl; }
    if (t == 0) cptr[nb] = lds[127];
}

// ---- pass A: LDS-binned coarse bucket scatter (coalesced staged writes) -----
// staged record: (val fp32, meta = (lrow11<<18)|col)
__global__ void bucket_scatter(const void* __restrict__ vals, const int* __restrict__ rows,
                               const int* __restrict__ cols, int* __restrict__ bcur,
                               float2* __restrict__ staged, int nnz, int nbuck,
                               const int* __restrict__ flagp) {
    __shared__ int hist[NBMAX];
    __shared__ int exb[NBMAX];
    __shared__ int gb[NBMAX];
    __shared__ int sc[NBMAX];
    __shared__ float2 st[TILE];
    __shared__ int bkt[TILE];
    int t = threadIdx.x;
    int bf = *flagp;

    for (int tile = blockIdx.x * TILE; tile < nnz; tile += gridDim.x * TILE) {
        int cnt = min(TILE, nnz - tile);
        for (int i = t; i < NBMAX; i += 256) hist[i] = 0;
        __syncthreads();

        int   myb[16], myo[16], mmeta[16];
        float mv[16];
#pragma unroll
        for (int k = 0; k < 16; ++k) {
            int i = tile + k * 256 + t;            // coalesced
            if (i < nnz && (k * 256 + t) < cnt) {
                int r = rows[i], c = cols[i];
                mv[k]    = ld_elem(vals, i, bf);
                myb[k]   = r >> BSHIFT;
                mmeta[k] = ((r & (BROWS - 1)) << 18) | c;
                myo[k]   = atomicAdd(&hist[myb[k]], 1);
            } else myb[k] = -1;
        }
        __syncthreads();

        if (t < NBMAX) sc[t] = hist[t];
        __syncthreads();
        for (int off = 1; off < NBMAX; off <<= 1) {
            int v = 0;
            if (t < NBMAX) { v = sc[t]; if (t >= off) v += sc[t - off]; }
            __syncthreads();
            if (t < NBMAX) sc[t] = v;
            __syncthreads();
        }
        if (t < NBMAX) {
            exb[t] = sc[t] - hist[t];
            if (t < nbuck && hist[t] > 0) gb[t] = atomicAdd(&bcur[t], hist[t]);
        }
        __syncthreads();

#pragma unroll
        for (int k = 0; k < 16; ++k) {
            if (myb[k] >= 0) {
                int p = exb[myb[k]] + myo[k];
                st[p]  = make_float2(mv[k], __int_as_float(mmeta[k]));
                bkt[p] = myb[k];
            }
        }
        __syncthreads();

        for (int p = t; p < cnt; p += 256) {
            int b = bkt[p];
            staged[gb[b] + (p - exb[b])] = st[p];
        }
        __syncthreads();
    }
}

// ---- pass B (fused): per-bucket row hist + LDS scan + row_ptr + placement ---
// One block (512 thr) per coarse bucket. Produces global row-exact CSR.
__global__ void bucket_csr(const int* __restrict__ cptr,
                           const float2* __restrict__ staged,
                           float2* __restrict__ edges,
                           int* __restrict__ row_ptr, int nrows, int nbuck) {
    __shared__ int rcnt[BROWS];   // 8 KB: per-row counts -> excl offsets -> cursors
    __shared__ int ssum[512];
    int b = blockIdx.x;
    int t = threadIdx.x;          // 512 threads
    int cbeg = cptr[b], cend = cptr[b + 1];
    int rlo = b << BSHIFT;
    int nr = min(BROWS, nrows - rlo);

    for (int i = t; i < BROWS; i += 512) rcnt[i] = 0;
    __syncthreads();

    // pass 1: per-row counts (LDS atomics, low contention)
    const int* sm = (const int*)staged;
    for (int i = cbeg + t; i < cend; i += 512) {
        int lr = (sm[2 * i + 1] >> 18) & (BROWS - 1);
        atomicAdd(&rcnt[lr], 1);
    }
    __syncthreads();

    // exclusive scan of 2048 counters: 4 per thread + block scan
    int base = t * 4;
    int loc[4]; int s = 0;
#pragma unroll
    for (int k = 0; k < 4; ++k) { loc[k] = rcnt[base + k]; s += loc[k]; }
    ssum[t] = s;
    __syncthreads();
    for (int off = 1; off < 512; off <<= 1) {
        int x = ssum[t];
        int a = (t >= off) ? ssum[t - off] : 0;
        __syncthreads();
        ssum[t] = x + a;
        __syncthreads();
    }
    int run = (t > 0) ? ssum[t - 1] : 0;
#pragma unroll
    for (int k = 0; k < 4; ++k) { int c = loc[k]; rcnt[base + k] = run; run += c; }
    __syncthreads();

    // emit global row_ptr (coalesced)
    for (int i = t; i < nr; i += 512) row_ptr[rlo + i] = cbeg + rcnt[i];
    if (b == nbuck - 1 && t == 0) row_ptr[nrows] = cend;

    // pass 2: row-exact placement (L2-local window, LDS cursors)
    for (int i = cbeg + t; i < cend; i += 512) {
        float2 rec = staged[i];
        int meta = __float_as_int(rec.y);
        int lr = (meta >> 18) & (BROWS - 1);
        int c  = meta & 0x3FFFF;
        int pos = atomicAdd(&rcnt[lr], 1);
        edges[cbeg + pos] = make_float2(rec.x, __int_as_float(c));
    }
}

// ---- gather-only SpMM: 8 rows per wave, 8 lanes per row, lane = 8 dims ------
// GMODE: 0 = gather x0 (inputs, dtype via flag), 1 = gather fp16 g
// OMODE: 1 = write g' = x0 + acc as fp16, 3 = final (x0+acc)*0.25 (dtype via flag)
template <int GMODE, int OMODE>
__global__ void spmm_csr8(const int* __restrict__ row_ptr,
                          const float2* __restrict__ edges,
                          const void* __restrict__ uw, const void* __restrict__ iw,
                          int n_user_elems,
                          const __half* __restrict__ gin, void* __restrict__ gout,
                          int nrows, const int* __restrict__ flagp) {
    int tid  = blockIdx.x * blockDim.x + threadIdx.x;
    int wave = tid >> 6;
    int lane = threadIdx.x & 63;
    int g    = lane >> 3;          // row slot within wave (0..7)
    int l    = lane & 7;           // dim octet: covers dims [8l, 8l+7]
    int wid  = wave * 8 + g;
    if (wid >= nrows) return;
    int bf = *flagp;
    int beg = row_ptr[wid], end = row_ptr[wid + 1];
    float4 accA = make_float4(0.f, 0.f, 0.f, 0.f);
    float4 accB = make_float4(0.f, 0.f, 0.f, 0.f);

#define GATHER(E, X) { \
        long long ce = (long long)__float_as_int((E).y) * EMB + l * 8; \
        if (GMODE == 0) X = ld8_x0(uw, iw, n_user_elems, ce, bf); \
        else            X = ld8_f16(gin, ce); }
#define ACC(E, X) { float v = (E).x; \
        accA.x += v * (X).a.x; accA.y += v * (X).a.y; \
        accA.z += v * (X).a.z; accA.w += v * (X).a.w; \
        accB.x += v * (X).b.x; accB.y += v * (X).b.y; \
        accB.z += v * (X).b.z; accB.w += v * (X).b.w; }

    int j = beg;
    for (; j + 4 <= end; j += 4) {
        float2 e0 = edges[j], e1 = edges[j + 1], e2 = edges[j + 2], e3 = edges[j + 3];
        f8 xa, xb, xc, xd;
        GATHER(e0, xa); GATHER(e1, xb); GATHER(e2, xc); GATHER(e3, xd);
        ACC(e0, xa); ACC(e1, xb); ACC(e2, xc); ACC(e3, xd);
    }
    if (j + 2 <= end) {
        float2 e0 = edges[j], e1 = edges[j + 1];
        f8 xa, xb;
        GATHER(e0, xa); GATHER(e1, xb);
        ACC(e0, xa); ACC(e1, xb);
        j += 2;
    }
    if (j < end) {
        float2 e0 = edges[j];
        f8 xa; GATHER(e0, xa);
        ACC(e0, xa);
    }
#undef GATHER
#undef ACC

    long long re = (long long)wid * EMB + l * 8;
    f8 x0v = ld8_x0(uw, iw, n_user_elems, re, bf);
    float o0 = x0v.a.x + accA.x, o1 = x0v.a.y + accA.y;
    float o2 = x0v.a.z + accA.z, o3 = x0v.a.w + accA.w;
    float o4 = x0v.b.x + accB.x, o5 = x0v.b.y + accB.y;
    float o6 = x0v.b.z + accB.z, o7 = x0v.b.w + accB.w;

    if (OMODE == 1) {
        union { __half2 h; unsigned int u; } p0, p1, p2, p3;
        p0.h = __floats2half2_rn(o0, o1);
        p1.h = __floats2half2_rn(o2, o3);
        p2.h = __floats2half2_rn(o4, o5);
        p3.h = __floats2half2_rn(o6, o7);
        uint4 out; out.x = p0.u; out.y = p1.u; out.z = p2.u; out.w = p3.u;
        *reinterpret_cast<uint4*>((__half*)gout + re) = out;
    } else {
        o0 *= 0.25f; o1 *= 0.25f; o2 *= 0.25f; o3 *= 0.25f;
        o4 *= 0.25f; o5 *= 0.25f; o6 *= 0.25f; o7 *= 0.25f;
        if (bf) {
            __hip_bfloat16 b0 = (__hip_bfloat16)o0, b1 = (__hip_bfloat16)o1;
            __hip_bfloat16 b2 = (__hip_bfloat16)o2, b3 = (__hip_bfloat16)o3;
            __hip_bfloat16 b4 = (__hip_bfloat16)o4, b5 = (__hip_bfloat16)o5;
            __hip_bfloat16 b6 = (__hip_bfloat16)o6, b7 = (__hip_bfloat16)o7;
            unsigned short s0 = *reinterpret_cast<unsigned short*>(&b0);
            unsigned short s1 = *reinterpret_cast<unsigned short*>(&b1);
            unsigned short s2 = *reinterpret_cast<unsigned short*>(&b2);
            unsigned short s3 = *reinterpret_cast<unsigned short*>(&b3);
            unsigned short s4 = *reinterpret_cast<unsigned short*>(&b4);
            unsigned short s5 = *reinterpret_cast<unsigned short*>(&b5);
            unsigned short s6 = *reinterpret_cast<unsigned short*>(&b6);
            unsigned short s7 = *reinterpret_cast<unsigned short*>(&b7);
            uint4 out;
            out.x = (unsigned int)s0 | ((unsigned int)s1 << 16);
            out.y = (unsigned int)s2 | ((unsigned int)s3 << 16);
            out.z = (unsigned int)s4 | ((unsigned int)s5 << 16);
            out.w = (unsigned int)s6 | ((unsigned int)s7 << 16);
            *reinterpret_cast<uint4*>((unsigned short*)gout + re) = out;
        } else {
            float4* fp = reinterpret_cast<float4*>((float*)gout + re);
            fp[0] = make_float4(o0, o1, o2, o3);
            fp[1] = make_float4(o4, o5, o6, o7);
        }
    }
}

extern "C" void kernel_launch(void* const* d_in, const int* in_sizes, int n_in,
                              void* d_out, int out_size, void* d_ws, size_t ws_size,
                              hipStream_t stream) {
    const void* uw   = d_in[0];
    const void* iw   = d_in[1];
    const void* vals = d_in[2];
    const int*  rows = (const int*)d_in[3];
    const int*  cols = (const int*)d_in[4];

    const int n_user = in_sizes[0];                // 6.4M elems
    const int total  = in_sizes[0] + in_sizes[1];  // 12.8M elems
    const int nnz    = in_sizes[2];                // 1M edges
    const int nrows  = total / EMB;                // 200K
    const int nbuck  = (nrows + BROWS - 1) >> BSHIFT;   // 98 coarse

    // ---- workspace layout (256B-aligned) ----
    char* p = (char*)d_ws;
    auto alloc = [&](size_t bytes) { char* q = p; p += (bytes + 255) & ~(size_t)255; return q; };
    int*    flag    = (int*)   alloc(sizeof(int));
    int*    counts  = (int*)   alloc(NBMAX * sizeof(int));
    int*    cptr    = (int*)   alloc((NBMAX + 1) * sizeof(int));
    int*    bcur    = (int*)   alloc(NBMAX * sizeof(int));
    int*    row_ptr = (int*)   alloc((size_t)(nrows + 1) * sizeof(int));
    float2* staged  = (float2*)alloc((size_t)nnz * sizeof(float2));
    float2* edges   = (float2*)alloc((size_t)nnz * sizeof(float2));
    size_t used = (size_t)(p - (char*)d_ws);
    size_t avail = (ws_size > used) ? ws_size - used : 0;

    const size_t g_f16 = (size_t)total * sizeof(__half);  // 25.6 MB
    __half *g2, *g3;
    if (avail >= 2 * g_f16 + 512) { g2 = (__half*)alloc(g_f16); g3 = (__half*)alloc(g_f16); }
    else { g2 = (__half*)d_out; g3 = (__half*)alloc(g_f16); }  // d_out dead-staged, overwritten at end

    // ---- row-exact CSR via coarse buckets (cheap build) ----
    hipMemsetAsync(counts, 0, NBMAX * sizeof(int), stream);
    hist_coarse<<<120, 256, 0, stream>>>(rows, counts, nnz, (const unsigned short*)vals, flag);
    scan_coarse<<<1, 128, 0, stream>>>(counts, cptr, bcur, nbuck);
    const int ntiles = (nnz + TILE - 1) / TILE;   // 245
    bucket_scatter<<<ntiles, 256, 0, stream>>>(vals, rows, cols, bcur, staged, nnz, nbuck, flag);
    bucket_csr<<<nbuck, 512, 0, stream>>>(cptr, staged, edges, row_ptr, nrows, nbuck);

    // ---- 3 gather-only SpMM layers (Horner), fp16 inter-layer staging ----
    const int nwaves = (nrows + 7) / 8;           // 8 rows per wave
    const int rb = (nwaves * 64 + 255) / 256;
    spmm_csr8<0, 1><<<rb, 256, 0, stream>>>(row_ptr, edges, uw, iw, n_user,
                                            nullptr, g2, nrows, flag);
    spmm_csr8<1, 1><<<rb, 256, 0, stream>>>(row_ptr, edges, uw, iw, n_user,
                                            g2, g3, nrows, flag);
    spmm_csr8<1, 3><<<rb, 256, 0, stream>>>(row_ptr, edges, uw, iw, n_user,
                                            g3, d_out, nrows, flag);
}

// Round 8
// 243.252 us; speedup vs baseline: 5.2643x; 1.0471x over previous
//
#include <hip/hip_runtime.h>
#include <hip/hip_bf16.h>
#include <hip/hip_fp16.h>

#define EMB 64
#define BSHIFT 10         // 1024 rows per coarse bucket
#define BROWS (1 << BSHIFT)
#define NBMAX 256         // >= ceil(200000/1024)=196
#define TILE 4096         // edges per bucket_scatter tile

// ---- dtype-flexible loads ---------------------------------------------------
__device__ __forceinline__ float ld_elem(const void* p, long long i, int bf) {
    if (bf) return (float)((const __hip_bfloat16*)p)[i];
    return ((const float*)p)[i];
}

struct f8 { float4 a, b; };

// load 8 consecutive elems (16B fp16/bf16, 32B fp32) — e is a multiple of 8
__device__ __forceinline__ f8 ld8_x0(const void* uw, const void* iw,
                                     int n_user_elems, long long e, int bf) {
    const void* base = uw;
    if (e >= (long long)n_user_elems) { base = iw; e -= n_user_elems; }
    f8 r;
    if (bf) {
        uint4 q = *reinterpret_cast<const uint4*>((const unsigned short*)base + e);
        r.a = make_float4(__uint_as_float((q.x & 0xFFFFu) << 16),
                          __uint_as_float(q.x & 0xFFFF0000u),
                          __uint_as_float((q.y & 0xFFFFu) << 16),
                          __uint_as_float(q.y & 0xFFFF0000u));
        r.b = make_float4(__uint_as_float((q.z & 0xFFFFu) << 16),
                          __uint_as_float(q.z & 0xFFFF0000u),
                          __uint_as_float((q.w & 0xFFFFu) << 16),
                          __uint_as_float(q.w & 0xFFFF0000u));
    } else {
        const float4* f = reinterpret_cast<const float4*>((const float*)base + e);
        r.a = f[0]; r.b = f[1];
    }
    return r;
}

__device__ __forceinline__ f8 ld8_f16(const __half* g, long long e) {
    uint4 q = *reinterpret_cast<const uint4*>(g + e);
    union { unsigned int u; __half2 h; } c;
    f8 r;
    c.u = q.x; float2 f0 = __half22float2(c.h);
    c.u = q.y; float2 f1 = __half22float2(c.h);
    c.u = q.z; float2 f2 = __half22float2(c.h);
    c.u = q.w; float2 f3 = __half22float2(c.h);
    r.a = make_float4(f0.x, f0.y, f1.x, f1.y);
    r.b = make_float4(f2.x, f2.y, f3.x, f3.y);
    return r;
}

// ---- coarse histogram (LDS-privatized, int4 reads) + parallel dtype probe ---
__global__ void hist_coarse(const int* __restrict__ rows, int* __restrict__ counts, int nnz,
                            const unsigned short* __restrict__ v16, int* __restrict__ flag) {
    __shared__ int h[NBMAX];
    __shared__ int probe;
    int t = threadIdx.x;
    h[t] = 0;
    if (t == 0) probe = 0;
    __syncthreads();
    int tid = blockIdx.x * blockDim.x + t;
    int stride = gridDim.x * blockDim.x;
    const int4* r4 = reinterpret_cast<const int4*>(rows);
    int nv = nnz >> 2;
    for (int i = tid; i < nv; i += stride) {
        int4 r = r4[i];
        atomicAdd(&h[r.x >> BSHIFT], 1);
        atomicAdd(&h[r.y >> BSHIFT], 1);
        atomicAdd(&h[r.z >> BSHIFT], 1);
        atomicAdd(&h[r.w >> BSHIFT], 1);
    }
    for (int i = (nv << 2) + tid; i < nnz; i += stride) atomicAdd(&h[rows[i] >> BSHIFT], 1);
    if (blockIdx.x == 0) {           // parallel probe: 256 threads x 1 value
        unsigned int hb = v16[t] >> 8;
        unsigned int ex = hb & 0x7F;
        if (hb < 0x80 && ex >= 0x30 && ex < 0x40) atomicAdd(&probe, 1);
    }
    __syncthreads();
    { int v = h[t]; if (v) atomicAdd(&counts[t], v); }
    if (blockIdx.x == 0 && t == 0) *flag = (probe >= 200) ? 1 : 0;
}

// ---- tiny scan over coarse buckets (1 block, 256 threads) -------------------
__global__ void scan_coarse(const int* __restrict__ counts, int* __restrict__ cptr,
                            int* __restrict__ bcur, int nb) {
    __shared__ int lds[NBMAX];
    int t = threadIdx.x;                 // blockDim = 256 >= nb
    int v = (t < nb) ? counts[t] : 0;
    lds[t] = v;
    __syncthreads();
    for (int off = 1; off < NBMAX; off <<= 1) {
        int x = lds[t];
        int a = (t >= off) ? lds[t - off] : 0;
        __syncthreads();
        lds[t] = x + a;
        __syncthreads();
    }
    if (t < nb) { int excl = lds[t] - v; cptr[t] = excl; bcur[t] = excl; }
    if (t == 0) cptr[nb] = lds[NBMAX - 1];
}

// ---- pass A: LDS-binned coarse bucket scatter (coalesced staged writes) -----
// staged record: (val fp32, meta = (lrow10<<18)|col)
__global__ void bucket_scatter(const void* __restrict__ vals, const int* __restrict__ rows,
                               const int* __restrict__ cols, int* __restrict__ bcur,
                               float2* __restrict__ staged, int nnz, int nbuck,
                               const int* __restrict__ flagp) {
    __shared__ int hist[NBMAX];
    __shared__ int exb[NBMAX];
    __shared__ int gb[NBMAX];
    __shared__ int sc[NBMAX];
    __shared__ float2 st[TILE];
    __shared__ int bkt[TILE];
    int t = threadIdx.x;   // 256
    int bf = *flagp;

    for (int tile = blockIdx.x * TILE; tile < nnz; tile += gridDim.x * TILE) {
        int cnt = min(TILE, nnz - tile);
        hist[t] = 0;
        __syncthreads();

        int   myb[16], myo[16], mmeta[16];
        float mv[16];
#pragma unroll
        for (int k = 0; k < 16; ++k) {
            int i = tile + k * 256 + t;            // coalesced
            if (i < nnz && (k * 256 + t) < cnt) {
                int r = rows[i], c = cols[i];
                mv[k]    = ld_elem(vals, i, bf);
                myb[k]   = r >> BSHIFT;
                mmeta[k] = ((r & (BROWS - 1)) << 18) | c;
                myo[k]   = atomicAdd(&hist[myb[k]], 1);
            } else myb[k] = -1;
        }
        __syncthreads();

        sc[t] = hist[t];
        __syncthreads();
        for (int off = 1; off < NBMAX; off <<= 1) {
            int v = sc[t];
            int a = (t >= off) ? sc[t - off] : 0;
            __syncthreads();
            sc[t] = v + a;
            __syncthreads();
        }
        exb[t] = sc[t] - hist[t];
        if (t < nbuck && hist[t] > 0) gb[t] = atomicAdd(&bcur[t], hist[t]);
        __syncthreads();

#pragma unroll
        for (int k = 0; k < 16; ++k) {
            if (myb[k] >= 0) {
                int p = exb[myb[k]] + myo[k];
                st[p]  = make_float2(mv[k], __int_as_float(mmeta[k]));
                bkt[p] = myb[k];
            }
        }
        __syncthreads();

        for (int p = t; p < cnt; p += 256) {
            int b = bkt[p];
            staged[gb[b] + (p - exb[b])] = st[p];
        }
        __syncthreads();
    }
}

// ---- pass B (fused): per-bucket row hist + LDS scan + row_ptr + placement ---
// One block (512 thr) per coarse bucket. Produces global row-exact CSR.
__global__ void bucket_csr(const int* __restrict__ cptr,
                           const float2* __restrict__ staged,
                           float2* __restrict__ edges,
                           int* __restrict__ row_ptr, int nrows, int nbuck) {
    __shared__ int rcnt[BROWS];   // 4 KB: per-row counts -> excl offsets -> cursors
    __shared__ int ssum[512];
    int b = blockIdx.x;
    int t = threadIdx.x;          // 512 threads
    int cbeg = cptr[b], cend = cptr[b + 1];
    int rlo = b << BSHIFT;
    int nr = min(BROWS, nrows - rlo);

    for (int i = t; i < BROWS; i += 512) rcnt[i] = 0;
    __syncthreads();

    // pass 1: per-row counts (LDS atomics, low contention)
    const int* sm = (const int*)staged;
    for (int i = cbeg + t; i < cend; i += 512) {
        int lr = (sm[2 * i + 1] >> 18) & (BROWS - 1);
        atomicAdd(&rcnt[lr], 1);
    }
    __syncthreads();

    // exclusive scan of 1024 counters: 2 per thread + block scan
    int base = t * 2;
    int l0 = rcnt[base], l1 = rcnt[base + 1];
    ssum[t] = l0 + l1;
    __syncthreads();
    for (int off = 1; off < 512; off <<= 1) {
        int x = ssum[t];
        int a = (t >= off) ? ssum[t - off] : 0;
        __syncthreads();
        ssum[t] = x + a;
        __syncthreads();
    }
    int run = (t > 0) ? ssum[t - 1] : 0;
    rcnt[base] = run;
    rcnt[base + 1] = run + l0;
    __syncthreads();

    // emit global row_ptr (coalesced)
    for (int i = t; i < nr; i += 512) row_ptr[rlo + i] = cbeg + rcnt[i];
    if (b == nbuck - 1 && t == 0) row_ptr[nrows] = cend;
    __syncthreads();   // RACE FIX: pass 2 mutates rcnt; all row_ptr reads of
                       // rcnt (exclusive offsets) must complete first.

    // pass 2: row-exact placement (L2-local window, LDS cursors)
    for (int i = cbeg + t; i < cend; i += 512) {
        float2 rec = staged[i];
        int meta = __float_as_int(rec.y);
        int lr = (meta >> 18) & (BROWS - 1);
        int c  = meta & 0x3FFFF;
        int pos = atomicAdd(&rcnt[lr], 1);
        edges[cbeg + pos] = make_float2(rec.x, __int_as_float(c));
    }
}

// ---- gather-only SpMM: 8 rows per wave, 8 lanes per row, lane = 8 dims ------
// GMODE: 0 = gather x0 (inputs, dtype via flag), 1 = gather fp16 g
// OMODE: 1 = write g' = x0 + acc as fp16, 3 = final (x0+acc)*0.25 (dtype via flag)
template <int GMODE, int OMODE>
__global__ void spmm_csr8(const int* __restrict__ row_ptr,
                          const float2* __restrict__ edges,
                          const void* __restrict__ uw, const void* __restrict__ iw,
                          int n_user_elems,
                          const __half* __restrict__ gin, void* __restrict__ gout,
                          int nrows, const int* __restrict__ flagp) {
    int tid  = blockIdx.x * blockDim.x + threadIdx.x;
    int wave = tid >> 6;
    int lane = threadIdx.x & 63;
    int g    = lane >> 3;          // row slot within wave (0..7)
    int l    = lane & 7;           // dim octet: covers dims [8l, 8l+7]
    int wid  = wave * 8 + g;
    if (wid >= nrows) return;
    int bf = *flagp;
    int beg = row_ptr[wid], end = row_ptr[wid + 1];
    float4 accA = make_float4(0.f, 0.f, 0.f, 0.f);
    float4 accB = make_float4(0.f, 0.f, 0.f, 0.f);

#define GATHER(E, X) { \
        long long ce = (long long)__float_as_int((E).y) * EMB + l * 8; \
        if (GMODE == 0) X = ld8_x0(uw, iw, n_user_elems, ce, bf); \
        else            X = ld8_f16(gin, ce); }
#define ACC(E, X) { float v = (E).x; \
        accA.x += v * (X).a.x; accA.y += v * (X).a.y; \
        accA.z += v * (X).a.z; accA.w += v * (X).a.w; \
        accB.x += v * (X).b.x; accB.y += v * (X).b.y; \
        accB.z += v * (X).b.z; accB.w += v * (X).b.w; }

    int j = beg;
    for (; j + 4 <= end; j += 4) {
        float2 e0 = edges[j], e1 = edges[j + 1], e2 = edges[j + 2], e3 = edges[j + 3];
        f8 xa, xb, xc, xd;
        GATHER(e0, xa); GATHER(e1, xb); GATHER(e2, xc); GATHER(e3, xd);
        ACC(e0, xa); ACC(e1, xb); ACC(e2, xc); ACC(e3, xd);
    }
    if (j + 2 <= end) {
        float2 e0 = edges[j], e1 = edges[j + 1];
        f8 xa, xb;
        GATHER(e0, xa); GATHER(e1, xb);
        ACC(e0, xa); ACC(e1, xb);
        j += 2;
    }
    if (j < end) {
        float2 e0 = edges[j];
        f8 xa; GATHER(e0, xa);
        ACC(e0, xa);
    }
#undef GATHER
#undef ACC

    long long re = (long long)wid * EMB + l * 8;
    f8 x0v = ld8_x0(uw, iw, n_user_elems, re, bf);
    float o0 = x0v.a.x + accA.x, o1 = x0v.a.y + accA.y;
    float o2 = x0v.a.z + accA.z, o3 = x0v.a.w + accA.w;
    float o4 = x0v.b.x + accB.x, o5 = x0v.b.y + accB.y;
    float o6 = x0v.b.z + accB.z, o7 = x0v.b.w + accB.w;

    if (OMODE == 1) {
        union { __half2 h; unsigned int u; } p0, p1, p2, p3;
        p0.h = __floats2half2_rn(o0, o1);
        p1.h = __floats2half2_rn(o2, o3);
        p2.h = __floats2half2_rn(o4, o5);
        p3.h = __floats2half2_rn(o6, o7);
        uint4 out; out.x = p0.u; out.y = p1.u; out.z = p2.u; out.w = p3.u;
        *reinterpret_cast<uint4*>((__half*)gout + re) = out;
    } else {
        o0 *= 0.25f; o1 *= 0.25f; o2 *= 0.25f; o3 *= 0.25f;
        o4 *= 0.25f; o5 *= 0.25f; o6 *= 0.25f; o7 *= 0.25f;
        if (bf) {
            __hip_bfloat16 b0 = (__hip_bfloat16)o0, b1 = (__hip_bfloat16)o1;
            __hip_bfloat16 b2 = (__hip_bfloat16)o2, b3 = (__hip_bfloat16)o3;
            __hip_bfloat16 b4 = (__hip_bfloat16)o4, b5 = (__hip_bfloat16)o5;
            __hip_bfloat16 b6 = (__hip_bfloat16)o6, b7 = (__hip_bfloat16)o7;
            unsigned short s0 = *reinterpret_cast<unsigned short*>(&b0);
            unsigned short s1 = *reinterpret_cast<unsigned short*>(&b1);
            unsigned short s2 = *reinterpret_cast<unsigned short*>(&b2);
            unsigned short s3 = *reinterpret_cast<unsigned short*>(&b3);
            unsigned short s4 = *reinterpret_cast<unsigned short*>(&b4);
            unsigned short s5 = *reinterpret_cast<unsigned short*>(&b5);
            unsigned short s6 = *reinterpret_cast<unsigned short*>(&b6);
            unsigned short s7 = *reinterpret_cast<unsigned short*>(&b7);
            uint4 out;
            out.x = (unsigned int)s0 | ((unsigned int)s1 << 16);
            out.y = (unsigned int)s2 | ((unsigned int)s3 << 16);
            out.z = (unsigned int)s4 | ((unsigned int)s5 << 16);
            out.w = (unsigned int)s6 | ((unsigned int)s7 << 16);
            *reinterpret_cast<uint4*>((unsigned short*)gout + re) = out;
        } else {
            float4* fp = reinterpret_cast<float4*>((float*)gout + re);
            fp[0] = make_float4(o0, o1, o2, o3);
            fp[1] = make_float4(o4, o5, o6, o7);
        }
    }
}

extern "C" void kernel_launch(void* const* d_in, const int* in_sizes, int n_in,
                              void* d_out, int out_size, void* d_ws, size_t ws_size,
                              hipStream_t stream) {
    const void* uw   = d_in[0];
    const void* iw   = d_in[1];
    const void* vals = d_in[2];
    const int*  rows = (const int*)d_in[3];
    const int*  cols = (const int*)d_in[4];

    const int n_user = in_sizes[0];                // 6.4M elems
    const int total  = in_sizes[0] + in_sizes[1];  // 12.8M elems
    const int nnz    = in_sizes[2];                // 1M edges
    const int nrows  = total / EMB;                // 200K
    const int nbuck  = (nrows + BROWS - 1) >> BSHIFT;   // 196 coarse

    // ---- workspace layout (256B-aligned) ----
    char* p = (char*)d_ws;
    auto alloc = [&](size_t bytes) { char* q = p; p += (bytes + 255) & ~(size_t)255; return q; };
    int*    flag    = (int*)   alloc(sizeof(int));
    int*    counts  = (int*)   alloc(NBMAX * sizeof(int));
    int*    cptr    = (int*)   alloc((NBMAX + 1) * sizeof(int));
    int*    bcur    = (int*)   alloc(NBMAX * sizeof(int));
    int*    row_ptr = (int*)   alloc((size_t)(nrows + 1) * sizeof(int));
    float2* staged  = (float2*)alloc((size_t)nnz * sizeof(float2));
    float2* edges   = (float2*)alloc((size_t)nnz * sizeof(float2));
    size_t used = (size_t)(p - (char*)d_ws);
    size_t avail = (ws_size > used) ? ws_size - used : 0;

    const size_t g_f16 = (size_t)total * sizeof(__half);  // 25.6 MB
    __half *g2, *g3;
    if (avail >= 2 * g_f16 + 512) { g2 = (__half*)alloc(g_f16); g3 = (__half*)alloc(g_f16); }
    else { g2 = (__half*)d_out; g3 = (__half*)alloc(g_f16); }  // d_out dead-staged, overwritten at end

    // ---- row-exact CSR via coarse buckets (cheap build) ----
    hipMemsetAsync(counts, 0, NBMAX * sizeof(int), stream);
    hist_coarse<<<256, 256, 0, stream>>>(rows, counts, nnz, (const unsigned short*)vals, flag);
    scan_coarse<<<1, 256, 0, stream>>>(counts, cptr, bcur, nbuck);
    const int ntiles = (nnz + TILE - 1) / TILE;   // 245
    bucket_scatter<<<ntiles, 256, 0, stream>>>(vals, rows, cols, bcur, staged, nnz, nbuck, flag);
    bucket_csr<<<nbuck, 512, 0, stream>>>(cptr, staged, edges, row_ptr, nrows, nbuck);

    // ---- 3 gather-only SpMM layers (Horner), fp16 inter-layer staging ----
    const int nwaves = (nrows + 7) / 8;           // 8 rows per wave
    const int rb = (nwaves * 64 + 255) / 256;
    spmm_csr8<0, 1><<<rb, 256, 0, stream>>>(row_ptr, edges, uw, iw, n_user,
                                            nullptr, g2, nrows, flag);
    spmm_csr8<1, 1><<<rb, 256, 0, stream>>>(row_ptr, edges, uw, iw, n_user,
                                            g2, g3, nrows, flag);
    spmm_csr8<1, 3><<<rb, 256, 0, stream>>>(row_ptr, edges, uw, iw, n_user,
                                            g3, d_out, nrows, flag);
}